// Round 1
// baseline (1124.063 us; speedup 1.0000x reference)
//
#include <hip/hip_runtime.h>

// ScaledDotProductAttention: out = softmax((q/T) @ k^T * mask) @ v
// B=4 H=16 S=2048 D=64, f32 in/out, multiplicative mask (1,1,S,S).
// Round 1: f32 vector-ALU flash baseline. One query row per thread;
// online softmax fully register-local (no cross-lane). K/V tiles in LDS,
// broadcast reads (all lanes same address -> conflict-free).

constexpr int Bc = 4, Hc = 16, Sc = 2048, Dc = 64;
constexpr int QT = 256;   // queries per block = blockDim.x (1 query/thread)
constexpr int KT = 64;    // keys per LDS tile
constexpr int SUB = 16;   // keys per score sub-chunk (register array)
constexpr float INV_T = 0.125f;  // 1/8

__global__ __launch_bounds__(QT)
void attn_f32(const float* __restrict__ Q, const float* __restrict__ K,
              const float* __restrict__ V, const float* __restrict__ M,
              float* __restrict__ O)
{
    __shared__ float Kt[KT][Dc];  // 16 KB
    __shared__ float Vt[KT][Dc];  // 16 KB

    const int tid  = threadIdx.x;
    const int nqt  = Sc / QT;               // 8
    const int bh   = blockIdx.x / nqt;      // 0..63
    const int qt   = blockIdx.x % nqt;
    const int qrow = qt * QT + tid;

    const float* qp = Q + ((size_t)bh * Sc + qrow) * Dc;
    const float* mp = M + (size_t)qrow * Sc;          // mask row (shared over bh)
    const float* kb = K + (size_t)bh * Sc * Dc;
    const float* vb = V + (size_t)bh * Sc * Dc;

    // Q row pre-scaled by 1/T into registers
    float qv[Dc];
#pragma unroll
    for (int d = 0; d < Dc; d += 4) {
        float4 t = *reinterpret_cast<const float4*>(qp + d);
        qv[d+0] = t.x * INV_T; qv[d+1] = t.y * INV_T;
        qv[d+2] = t.z * INV_T; qv[d+3] = t.w * INV_T;
    }

    float acc[Dc];
#pragma unroll
    for (int d = 0; d < Dc; ++d) acc[d] = 0.f;
    float mrun = -1e30f, lrun = 0.f;

    for (int k0 = 0; k0 < Sc; k0 += KT) {
        __syncthreads();   // previous tile fully consumed
        {
            // 64x64 f32 K and V tiles: 4096 floats each, 256 threads ->
            // 4 float4 per thread per tile, fully coalesced.
            const float4* ks = reinterpret_cast<const float4*>(kb + (size_t)k0 * Dc);
            const float4* vs = reinterpret_cast<const float4*>(vb + (size_t)k0 * Dc);
            float4* kd = reinterpret_cast<float4*>(&Kt[0][0]);
            float4* vd = reinterpret_cast<float4*>(&Vt[0][0]);
#pragma unroll
            for (int i = 0; i < (KT * Dc / 4) / QT; ++i) {   // 4 iters
                kd[tid + QT * i] = ks[tid + QT * i];
                vd[tid + QT * i] = vs[tid + QT * i];
            }
        }
        __syncthreads();

        for (int j0 = 0; j0 < KT; j0 += SUB) {   // 4 sub-chunks, not unrolled
            // mask values for this thread's row, 16 keys
            float mk[SUB];
#pragma unroll
            for (int i = 0; i < SUB; i += 4) {
                float4 t = *reinterpret_cast<const float4*>(mp + k0 + j0 + i);
                mk[i+0] = t.x; mk[i+1] = t.y; mk[i+2] = t.z; mk[i+3] = t.w;
            }

            // scores: 16 independent FMA chains (ILP), LDS broadcast reads
            float s[SUB];
#pragma unroll
            for (int j = 0; j < SUB; ++j) s[j] = 0.f;
#pragma unroll
            for (int d = 0; d < Dc; d += 4) {
#pragma unroll
                for (int j = 0; j < SUB; ++j) {
                    float4 kv = *reinterpret_cast<const float4*>(&Kt[j0 + j][d]);
                    s[j] = fmaf(qv[d+0], kv.x, s[j]);
                    s[j] = fmaf(qv[d+1], kv.y, s[j]);
                    s[j] = fmaf(qv[d+2], kv.z, s[j]);
                    s[j] = fmaf(qv[d+3], kv.w, s[j]);
                }
            }

            // multiplicative mask BEFORE softmax (masked -> score 0, still counted)
            float cmax = -1e30f;
#pragma unroll
            for (int j = 0; j < SUB; ++j) { s[j] *= mk[j]; cmax = fmaxf(cmax, s[j]); }

            if (cmax > mrun) {   // exec-masked; skipped once max stabilizes
                float r = __expf(mrun - cmax);
                mrun = cmax;
                lrun *= r;
#pragma unroll
                for (int d = 0; d < Dc; ++d) acc[d] *= r;
            }

#pragma unroll
            for (int j = 0; j < SUB; ++j) {
                float p = __expf(s[j] - mrun);
                lrun += p;
#pragma unroll
                for (int d = 0; d < Dc; d += 4) {
                    float4 vv = *reinterpret_cast<const float4*>(&Vt[j0 + j][d]);
                    acc[d+0] = fmaf(p, vv.x, acc[d+0]);
                    acc[d+1] = fmaf(p, vv.y, acc[d+1]);
                    acc[d+2] = fmaf(p, vv.z, acc[d+2]);
                    acc[d+3] = fmaf(p, vv.w, acc[d+3]);
                }
            }
        }
    }

    const float invl = 1.0f / lrun;
    float* op = O + ((size_t)bh * Sc + qrow) * Dc;
#pragma unroll
    for (int d = 0; d < Dc; d += 4) {
        float4 t;
        t.x = acc[d+0] * invl; t.y = acc[d+1] * invl;
        t.z = acc[d+2] * invl; t.w = acc[d+3] * invl;
        *reinterpret_cast<float4*>(op + d) = t;
    }
}

extern "C" void kernel_launch(void* const* d_in, const int* in_sizes, int n_in,
                              void* d_out, int out_size, void* d_ws, size_t ws_size,
                              hipStream_t stream) {
    const float* q = (const float*)d_in[0];
    const float* k = (const float*)d_in[1];
    const float* v = (const float*)d_in[2];
    const float* m = (const float*)d_in[3];
    float* out = (float*)d_out;
    dim3 grid(Bc * Hc * (Sc / QT));
    dim3 block(QT);
    attn_f32<<<grid, block, 0, stream>>>(q, k, v, m, out);
}

// Round 2
// 261.694 us; speedup vs baseline: 4.2953x; 4.2953x over previous
//
#include <hip/hip_runtime.h>
#include <hip/hip_bf16.h>

// bf16 MFMA flash attention, swapped-QK^T structure.
// B=4 H=16 S=2048 D=64, f32 in/out, multiplicative mask.
// out = softmax((q/T)@k^T * mask) @ v,  T=8. log2e folded into q-scale.

typedef __attribute__((ext_vector_type(4))) float  f32x4;
typedef __attribute__((ext_vector_type(8))) short  short8;
typedef __attribute__((ext_vector_type(4))) short  short4v;

constexpr int S = 2048, D = 64;
constexpr int NBH = 64;            // B*H
constexpr int QBLK = 128, KT = 64;
constexpr int NQT = S / QBLK;      // 16
constexpr int NKT = S / KT;        // 32
constexpr float SCALE = 0.125f * 1.44269504088896340736f;  // (1/T)*log2(e)

__device__ inline unsigned short bfb(float x) {
    union { __hip_bfloat16 h; unsigned short u; } cv;
    cv.h = __float2bfloat16(x);
    return cv.u;
}

__global__ __launch_bounds__(256, 2)
void attn_mfma(const float* __restrict__ Q, const float* __restrict__ K,
               const float* __restrict__ V, const float* __restrict__ M,
               float* __restrict__ O)
{
    // pad rows to 72 elems (144 B = 9*16 B): stride-9 rotation -> conflict-free b128 frag reads
    __shared__ short Kt[KT][72];      // bf16 bits, [key][d]
    __shared__ short Vt[D][72];       // transposed: [d][key]
    __shared__ short Pt[4][32][72];   // per-wave P, [qrow][key]

    const int tid  = threadIdx.x;
    const int w    = tid >> 6;
    const int lane = tid & 63;
    const int g    = lane >> 4;       // 16-lane group
    const int c    = lane & 15;

    const int bid = blockIdx.x;
    const int bh  = bid >> 4;         // bid = bh*16 + qt (qt cycles across XCDs)
    const int qt  = bid & 15;
    const int qw  = qt * QBLK + w * 32;   // this wave's first q-row

    const size_t bhS = (size_t)bh * S;

    // ---- Q fragments (B operand of swapped QK^T): bQ[rt][kk], k = d = kk*32 + g*8 + i
    short8 bQ[2][2];
#pragma unroll
    for (int rt = 0; rt < 2; ++rt) {
        const float* qp = Q + (bhS + qw + rt * 16 + c) * D;
#pragma unroll
        for (int kk = 0; kk < 2; ++kk) {
            const float* q8 = qp + kk * 32 + g * 8;
            float4 a = *reinterpret_cast<const float4*>(q8);
            float4 b = *reinterpret_cast<const float4*>(q8 + 4);
            short8 r;
            r[0] = bfb(a.x * SCALE); r[1] = bfb(a.y * SCALE);
            r[2] = bfb(a.z * SCALE); r[3] = bfb(a.w * SCALE);
            r[4] = bfb(b.x * SCALE); r[5] = bfb(b.y * SCALE);
            r[6] = bfb(b.z * SCALE); r[7] = bfb(b.w * SCALE);
            bQ[rt][kk] = r;
        }
    }

    const float* mrow0 = M + (size_t)(qw + c) * S;        // mask row, rt=0 (lane's q-row)
    const float* mrow1 = M + (size_t)(qw + 16 + c) * S;   // rt=1

    f32x4 acc[2][4] = {};             // PV accum: [rt][d-ntile], reg r -> qrow 4g+r, col c -> d
    float mR[2] = {-1e30f, -1e30f};   // running max (lane's q-row), log2 units
    float lR[2] = {0.f, 0.f};         // running denom

    for (int kt = 0; kt < NKT; ++kt) {
        const int k0 = kt * KT;
        __syncthreads();
        // ---- stage K (row-major) and V (transposed) as bf16
        {
            const float4* Ksrc = reinterpret_cast<const float4*>(K + (bhS + k0) * D);
            const float4* Vsrc = reinterpret_cast<const float4*>(V + (bhS + k0) * D);
#pragma unroll
            for (int i = 0; i < 4; ++i) {
                const int f = tid + 256 * i;       // float4 index in 64x64 tile
                const int key = f >> 4, dq = f & 15;
                float4 kv = Ksrc[f];
                short4v ks;
                ks[0] = bfb(kv.x); ks[1] = bfb(kv.y); ks[2] = bfb(kv.z); ks[3] = bfb(kv.w);
                *reinterpret_cast<short4v*>(&Kt[key][dq * 4]) = ks;
                float4 vv = Vsrc[f];
                Vt[dq * 4 + 0][key] = (short)bfb(vv.x);
                Vt[dq * 4 + 1][key] = (short)bfb(vv.y);
                Vt[dq * 4 + 2][key] = (short)bfb(vv.z);
                Vt[dq * 4 + 3][key] = (short)bfb(vv.w);
            }
        }
        __syncthreads();

        // ---- K fragments (A operand): row = key-in-ntile = c, k = d
        short8 aK[4][2];
#pragma unroll
        for (int n = 0; n < 4; ++n)
#pragma unroll
            for (int kk = 0; kk < 2; ++kk)
                aK[n][kk] = *reinterpret_cast<const short8*>(&Kt[n * 16 + c][kk * 32 + g * 8]);

        // ---- S^T = K · Q^T : C row = key offset (4g+r), col = q-row offset (c)
        f32x4 s[2][4] = {};
#pragma unroll
        for (int n = 0; n < 4; ++n)
#pragma unroll
            for (int rt = 0; rt < 2; ++rt)
#pragma unroll
                for (int kk = 0; kk < 2; ++kk)
                    s[rt][n] = __builtin_amdgcn_mfma_f32_16x16x32_bf16(
                        aK[n][kk], bQ[rt][kk], s[rt][n], 0, 0, 0);

        // ---- online softmax (per-lane q-row), multiplicative mask, P -> LDS
#pragma unroll
        for (int rt = 0; rt < 2; ++rt) {
            const float* mrow = rt ? mrow1 : mrow0;
            float sv[4][4];
            float smax = -1e30f;
#pragma unroll
            for (int n = 0; n < 4; ++n) {
                float4 mk = *reinterpret_cast<const float4*>(mrow + k0 + n * 16 + g * 4);
                sv[n][0] = s[rt][n][0] * mk.x;
                sv[n][1] = s[rt][n][1] * mk.y;
                sv[n][2] = s[rt][n][2] * mk.z;
                sv[n][3] = s[rt][n][3] * mk.w;
#pragma unroll
                for (int r = 0; r < 4; ++r) smax = fmaxf(smax, sv[n][r]);
            }
            smax = fmaxf(smax, __shfl_xor(smax, 16));
            smax = fmaxf(smax, __shfl_xor(smax, 32));
            const float mnew = fmaxf(mR[rt], smax);
            const float fr = exp2f(mR[rt] - mnew);
            mR[rt] = mnew;

            float rs = 0.f;
            float p[4][4];
#pragma unroll
            for (int n = 0; n < 4; ++n)
#pragma unroll
                for (int r = 0; r < 4; ++r) {
                    p[n][r] = exp2f(sv[n][r] - mnew);
                    rs += p[n][r];
                }
            rs += __shfl_xor(rs, 16);
            rs += __shfl_xor(rs, 32);
            lR[rt] = lR[rt] * fr + rs;

#pragma unroll
            for (int n = 0; n < 4; ++n) {
                short4v pk;
                pk[0] = bfb(p[n][0]); pk[1] = bfb(p[n][1]);
                pk[2] = bfb(p[n][2]); pk[3] = bfb(p[n][3]);
                *reinterpret_cast<short4v*>(&Pt[w][rt * 16 + c][n * 16 + g * 4]) = pk;
            }

            // redistribute rescale factor to PV accumulator layout (row = 4g+r)
            const float frd0 = __shfl(fr, 4 * g + 0);
            const float frd1 = __shfl(fr, 4 * g + 1);
            const float frd2 = __shfl(fr, 4 * g + 2);
            const float frd3 = __shfl(fr, 4 * g + 3);
#pragma unroll
            for (int n = 0; n < 4; ++n) {
                acc[rt][n][0] *= frd0; acc[rt][n][1] *= frd1;
                acc[rt][n][2] *= frd2; acc[rt][n][3] *= frd3;
            }
        }

        // ---- PV: A = P (row=qrow c, k=key), B = V (k=key, col=d c)
        short8 bV[4][2];
#pragma unroll
        for (int n = 0; n < 4; ++n)
#pragma unroll
            for (int kk = 0; kk < 2; ++kk)
                bV[n][kk] = *reinterpret_cast<const short8*>(&Vt[n * 16 + c][kk * 32 + g * 8]);
#pragma unroll
        for (int rt = 0; rt < 2; ++rt) {
#pragma unroll
            for (int kk = 0; kk < 2; ++kk) {
                short8 aP = *reinterpret_cast<const short8*>(&Pt[w][rt * 16 + c][kk * 32 + g * 8]);
#pragma unroll
                for (int n = 0; n < 4; ++n)
                    acc[rt][n] = __builtin_amdgcn_mfma_f32_16x16x32_bf16(
                        aP, bV[n][kk], acc[rt][n], 0, 0, 0);
            }
        }
    }

    // ---- epilogue: normalize and store (redistribute 1/l to row = 4g+r)
#pragma unroll
    for (int rt = 0; rt < 2; ++rt) {
        const float linv = 1.0f / lR[rt];
        float ld[4];
        ld[0] = __shfl(linv, 4 * g + 0);
        ld[1] = __shfl(linv, 4 * g + 1);
        ld[2] = __shfl(linv, 4 * g + 2);
        ld[3] = __shfl(linv, 4 * g + 3);
#pragma unroll
        for (int r = 0; r < 4; ++r) {
            float* op = O + (bhS + qw + rt * 16 + 4 * g + r) * D + c;
#pragma unroll
            for (int n = 0; n < 4; ++n) op[n * 16] = acc[rt][n][r] * ld[r];
        }
    }
}

extern "C" void kernel_launch(void* const* d_in, const int* in_sizes, int n_in,
                              void* d_out, int out_size, void* d_ws, size_t ws_size,
                              hipStream_t stream) {
    const float* q = (const float*)d_in[0];
    const float* k = (const float*)d_in[1];
    const float* v = (const float*)d_in[2];
    const float* m = (const float*)d_in[3];
    float* out = (float*)d_out;
    dim3 grid(NBH * NQT);   // 1024
    dim3 block(256);
    attn_mfma<<<grid, block, 0, stream>>>(q, k, v, m, out);
}

// Round 3
// 242.659 us; speedup vs baseline: 4.6323x; 1.0784x over previous
//
#include <hip/hip_runtime.h>
#include <hip/hip_bf16.h>

// bf16 MFMA flash attention, swapped-QK^T structure. R3:
//  + XOR-swizzled V-transpose store (kills 16-way LDS bank conflict)
//  + async staging: global loads for tile t+1 issued before compute of tile t
//  + defer-rescale: skip acc rescale when running max didn't grow
// B=4 H=16 S=2048 D=64, f32 in/out, multiplicative mask.

typedef __attribute__((ext_vector_type(4))) float  f32x4;
typedef __attribute__((ext_vector_type(8))) short  short8;
typedef __attribute__((ext_vector_type(4))) short  short4v;

constexpr int S = 2048, D = 64;
constexpr int NBH = 64;            // B*H
constexpr int QBLK = 128, KT = 64;
constexpr int NQT = S / QBLK;      // 16
constexpr int NKT = S / KT;        // 32
constexpr float SCALE = 0.125f * 1.44269504088896340736f;  // (1/T)*log2(e)

__device__ inline unsigned short bfb(float x) {
    union { __hip_bfloat16 h; unsigned short u; } cv;
    cv.h = __float2bfloat16(x);
    return cv.u;
}

__global__ __launch_bounds__(256, 2)
void attn_mfma(const float* __restrict__ Q, const float* __restrict__ K,
               const float* __restrict__ V, const float* __restrict__ M,
               float* __restrict__ O)
{
    // rows padded to 72 elems (144 B): b128 frag reads stay at phase-minimum
    __shared__ short Kt[KT][72];      // [key][d]
    __shared__ short Vt[D][72];       // transposed [d][key], key col XOR-swizzled by (row>>2)&7
    __shared__ short Pt[4][32][72];   // per-wave P, [qrow][key]

    const int tid  = threadIdx.x;
    const int w    = tid >> 6;
    const int lane = tid & 63;
    const int g    = lane >> 4;       // 16-lane group
    const int c    = lane & 15;

    const int bid = blockIdx.x;
    const int bh  = bid >> 4;
    const int qt  = bid & 15;
    const int qw  = qt * QBLK + w * 32;

    const size_t bhS = (size_t)bh * S;

    // staging decomposition: f = tid + 256*i -> (key, dq); thread loads V[key][dq*4..+3]
    const int skey = tid >> 4;        // base key for i=0 (i adds 16 each)
    const int sdq  = tid & 15;
    const int vswz = (sdq & 7) << 3;  // V store column swizzle (row>>2 == dq for all 4 rows)

    // ---- Q fragments (B operand): bQ[rt][kk], k = d = kk*32 + g*8 + i
    short8 bQ[2][2];
#pragma unroll
    for (int rt = 0; rt < 2; ++rt) {
        const float* qp = Q + (bhS + qw + rt * 16 + c) * D;
#pragma unroll
        for (int kk = 0; kk < 2; ++kk) {
            const float* q8 = qp + kk * 32 + g * 8;
            float4 a = *reinterpret_cast<const float4*>(q8);
            float4 b = *reinterpret_cast<const float4*>(q8 + 4);
            short8 r;
            r[0] = bfb(a.x * SCALE); r[1] = bfb(a.y * SCALE);
            r[2] = bfb(a.z * SCALE); r[3] = bfb(a.w * SCALE);
            r[4] = bfb(b.x * SCALE); r[5] = bfb(b.y * SCALE);
            r[6] = bfb(b.z * SCALE); r[7] = bfb(b.w * SCALE);
            bQ[rt][kk] = r;
        }
    }

    const float* mrow0 = M + (size_t)(qw + c) * S;
    const float* mrow1 = M + (size_t)(qw + 16 + c) * S;

    f32x4 acc[2][4] = {};
    float mR[2] = {-1e30f, -1e30f};
    float lR[2] = {0.f, 0.f};

    const float4* Kb4 = reinterpret_cast<const float4*>(K + bhS * D);
    const float4* Vb4 = reinterpret_cast<const float4*>(V + bhS * D);

    // ---- prologue: stage tile 0
    float4 kpre[4], vpre[4];
#pragma unroll
    for (int i = 0; i < 4; ++i) {
        kpre[i] = Kb4[tid + 256 * i];
        vpre[i] = Vb4[tid + 256 * i];
    }
#pragma unroll
    for (int i = 0; i < 4; ++i) {
        const int key = skey + 16 * i;
        short4v ks;
        ks[0] = bfb(kpre[i].x); ks[1] = bfb(kpre[i].y);
        ks[2] = bfb(kpre[i].z); ks[3] = bfb(kpre[i].w);
        *reinterpret_cast<short4v*>(&Kt[key][sdq * 4]) = ks;
        Vt[sdq * 4 + 0][key ^ vswz] = (short)bfb(vpre[i].x);
        Vt[sdq * 4 + 1][key ^ vswz] = (short)bfb(vpre[i].y);
        Vt[sdq * 4 + 2][key ^ vswz] = (short)bfb(vpre[i].z);
        Vt[sdq * 4 + 3][key ^ vswz] = (short)bfb(vpre[i].w);
    }
    __syncthreads();

    for (int kt = 0; kt < NKT; ++kt) {
        const int k0 = kt * KT;
        // ---- issue next tile's global loads (latency hides under compute)
        const int ktn = (kt + 1 < NKT) ? kt + 1 : kt;
        const size_t nb = (size_t)ktn * (KT * D / 4);
#pragma unroll
        for (int i = 0; i < 4; ++i) {
            kpre[i] = Kb4[nb + tid + 256 * i];
            vpre[i] = Vb4[nb + tid + 256 * i];
        }

        // ---- K fragments (A operand): row = key = n*16+c, k = d
        short8 aK[4][2];
#pragma unroll
        for (int n = 0; n < 4; ++n)
#pragma unroll
            for (int kk = 0; kk < 2; ++kk)
                aK[n][kk] = *reinterpret_cast<const short8*>(&Kt[n * 16 + c][kk * 32 + g * 8]);

        // ---- S^T = K · Q^T
        f32x4 s[2][4] = {};
#pragma unroll
        for (int n = 0; n < 4; ++n)
#pragma unroll
            for (int rt = 0; rt < 2; ++rt)
#pragma unroll
                for (int kk = 0; kk < 2; ++kk)
                    s[rt][n] = __builtin_amdgcn_mfma_f32_16x16x32_bf16(
                        aK[n][kk], bQ[rt][kk], s[rt][n], 0, 0, 0);

        // ---- online softmax (per-lane q-row), multiplicative mask
#pragma unroll
        for (int rt = 0; rt < 2; ++rt) {
            const float* mrow = rt ? mrow1 : mrow0;
            float sv[4][4];
            float smax = -1e30f;
#pragma unroll
            for (int n = 0; n < 4; ++n) {
                float4 mk = *reinterpret_cast<const float4*>(mrow + k0 + n * 16 + g * 4);
                sv[n][0] = s[rt][n][0] * mk.x;
                sv[n][1] = s[rt][n][1] * mk.y;
                sv[n][2] = s[rt][n][2] * mk.z;
                sv[n][3] = s[rt][n][3] * mk.w;
#pragma unroll
                for (int r = 0; r < 4; ++r) smax = fmaxf(smax, sv[n][r]);
            }
            smax = fmaxf(smax, __shfl_xor(smax, 16));
            smax = fmaxf(smax, __shfl_xor(smax, 32));

            if (__any(smax > mR[rt])) {   // wave-uniform; skipped once max stabilizes
                const float mnew = fmaxf(mR[rt], smax);
                const float fr = exp2f(mR[rt] - mnew);
                mR[rt] = mnew;
                lR[rt] *= fr;
                const float frd0 = __shfl(fr, 4 * g + 0);
                const float frd1 = __shfl(fr, 4 * g + 1);
                const float frd2 = __shfl(fr, 4 * g + 2);
                const float frd3 = __shfl(fr, 4 * g + 3);
#pragma unroll
                for (int n = 0; n < 4; ++n) {
                    acc[rt][n][0] *= frd0; acc[rt][n][1] *= frd1;
                    acc[rt][n][2] *= frd2; acc[rt][n][3] *= frd3;
                }
            }

            float rs = 0.f;
            float p[4][4];
#pragma unroll
            for (int n = 0; n < 4; ++n)
#pragma unroll
                for (int r = 0; r < 4; ++r) {
                    p[n][r] = exp2f(sv[n][r] - mR[rt]);
                    rs += p[n][r];
                }
            rs += __shfl_xor(rs, 16);
            rs += __shfl_xor(rs, 32);
            lR[rt] += rs;

#pragma unroll
            for (int n = 0; n < 4; ++n) {
                short4v pk;
                pk[0] = bfb(p[n][0]); pk[1] = bfb(p[n][1]);
                pk[2] = bfb(p[n][2]); pk[3] = bfb(p[n][3]);
                *reinterpret_cast<short4v*>(&Pt[w][rt * 16 + c][n * 16 + g * 4]) = pk;
            }
        }

        // ---- PV: A = P, B = V (swizzled read)
        short8 bV[4][2];
#pragma unroll
        for (int n = 0; n < 4; ++n) {
            const int vrow = n * 16 + c;
            const int vs = ((vrow >> 2) & 7) << 3;
#pragma unroll
            for (int kk = 0; kk < 2; ++kk)
                bV[n][kk] = *reinterpret_cast<const short8*>(&Vt[vrow][(kk * 32 + g * 8) ^ vs]);
        }
#pragma unroll
        for (int rt = 0; rt < 2; ++rt) {
#pragma unroll
            for (int kk = 0; kk < 2; ++kk) {
                short8 aP = *reinterpret_cast<const short8*>(&Pt[w][rt * 16 + c][kk * 32 + g * 8]);
#pragma unroll
                for (int n = 0; n < 4; ++n)
                    acc[rt][n] = __builtin_amdgcn_mfma_f32_16x16x32_bf16(
                        aP, bV[n][kk], acc[rt][n], 0, 0, 0);
            }
        }

        // ---- write next tile to LDS (loads drained here, after all waves done reading)
        __syncthreads();
#pragma unroll
        for (int i = 0; i < 4; ++i) {
            const int key = skey + 16 * i;
            short4v ks;
            ks[0] = bfb(kpre[i].x); ks[1] = bfb(kpre[i].y);
            ks[2] = bfb(kpre[i].z); ks[3] = bfb(kpre[i].w);
            *reinterpret_cast<short4v*>(&Kt[key][sdq * 4]) = ks;
            Vt[sdq * 4 + 0][key ^ vswz] = (short)bfb(vpre[i].x);
            Vt[sdq * 4 + 1][key ^ vswz] = (short)bfb(vpre[i].y);
            Vt[sdq * 4 + 2][key ^ vswz] = (short)bfb(vpre[i].z);
            Vt[sdq * 4 + 3][key ^ vswz] = (short)bfb(vpre[i].w);
        }
        __syncthreads();
    }

    // ---- epilogue: normalize and store
#pragma unroll
    for (int rt = 0; rt < 2; ++rt) {
        const float linv = 1.0f / lR[rt];
        float ld[4];
        ld[0] = __shfl(linv, 4 * g + 0);
        ld[1] = __shfl(linv, 4 * g + 1);
        ld[2] = __shfl(linv, 4 * g + 2);
        ld[3] = __shfl(linv, 4 * g + 3);
#pragma unroll
        for (int r = 0; r < 4; ++r) {
            float* op = O + (bhS + qw + rt * 16 + 4 * g + r) * D + c;
#pragma unroll
            for (int n = 0; n < 4; ++n) op[n * 16] = acc[rt][n][r] * ld[r];
        }
    }
}

extern "C" void kernel_launch(void* const* d_in, const int* in_sizes, int n_in,
                              void* d_out, int out_size, void* d_ws, size_t ws_size,
                              hipStream_t stream) {
    const float* q = (const float*)d_in[0];
    const float* k = (const float*)d_in[1];
    const float* v = (const float*)d_in[2];
    const float* m = (const float*)d_in[3];
    float* out = (float*)d_out;
    dim3 grid(NBH * NQT);   // 1024
    dim3 block(256);
    attn_mfma<<<grid, block, 0, stream>>>(q, k, v, m, out);
}

// Round 4
// 209.420 us; speedup vs baseline: 5.3675x; 1.1587x over previous
//
#include <hip/hip_runtime.h>
#include <hip/hip_bf16.h>

// R4: bf16 MFMA flash attention with pre-converted, pre-swizzled K/V tile
// images in d_ws. Staging = global_load_lds byte copy (no VALU, no conflicts).
// B=4 H=16 S=2048 D=64, f32 in/out, multiplicative mask.

typedef __attribute__((ext_vector_type(4))) float  f32x4;
typedef __attribute__((ext_vector_type(8))) short  short8;
typedef __attribute__((ext_vector_type(4))) short  short4v;

constexpr int S = 2048, D = 64;
constexpr int NBH = 64;
constexpr int QBLK = 128, KT = 64;
constexpr int NQT = S / QBLK;      // 16
constexpr int NKT = S / KT;        // 32
constexpr float SCALE = 0.125f * 1.44269504088896340736f;  // (1/T)*log2(e)
constexpr size_t TILE_SH = (size_t)KT * D;                 // 4096 shorts per tile image
constexpr size_t IMG_SH  = (size_t)NBH * NKT * TILE_SH;    // shorts per tensor image
constexpr size_t WS_NEED = 2 * IMG_SH * sizeof(short);     // 33.55 MB

__device__ inline unsigned short bfb(float x) {
    union { __hip_bfloat16 h; unsigned short u; } cv;
    cv.h = __float2bfloat16(x);
    return cv.u;
}

__device__ inline void gload16(const short* g, short* l) {
    auto gp = (const __attribute__((address_space(1))) int*)g;
    auto lp = (__attribute__((address_space(3))) int*)l;
    __builtin_amdgcn_global_load_lds(gp, lp, 16, 0, 0);
}

// ---- pre-pass: K -> swizzled bf16 tile images [key][d^8*(key&7)]
__global__ __launch_bounds__(256)
void conv_k(const float* __restrict__ K, short* __restrict__ Kimg) {
    const int t = threadIdx.x;
    const float* src = K + (size_t)blockIdx.x * TILE_SH;
    short* dst = Kimg + (size_t)blockIdx.x * TILE_SH;
    const int row = t >> 2, c16 = (t & 3) * 16;
    const int swz = (row & 7) << 3;
    float4 f0 = *reinterpret_cast<const float4*>(src + row * D + c16 + 0);
    float4 f1 = *reinterpret_cast<const float4*>(src + row * D + c16 + 4);
    float4 f2 = *reinterpret_cast<const float4*>(src + row * D + c16 + 8);
    float4 f3 = *reinterpret_cast<const float4*>(src + row * D + c16 + 12);
    short8 a, b;
    a[0]=bfb(f0.x); a[1]=bfb(f0.y); a[2]=bfb(f0.z); a[3]=bfb(f0.w);
    a[4]=bfb(f1.x); a[5]=bfb(f1.y); a[6]=bfb(f1.z); a[7]=bfb(f1.w);
    b[0]=bfb(f2.x); b[1]=bfb(f2.y); b[2]=bfb(f2.z); b[3]=bfb(f2.w);
    b[4]=bfb(f3.x); b[5]=bfb(f3.y); b[6]=bfb(f3.z); b[7]=bfb(f3.w);
    *reinterpret_cast<short8*>(dst + row * 64 + (c16 ^ swz)) = a;
    *reinterpret_cast<short8*>(dst + row * 64 + ((c16 + 8) ^ swz)) = b;
}

// ---- pre-pass: V -> transposed swizzled bf16 tile images [d][key^8*(d&7)]
__global__ __launch_bounds__(256)
void conv_v(const float* __restrict__ V, short* __restrict__ Vimg) {
    __shared__ float tl[64][65];
    const int t = threadIdx.x;
    const float* src = V + (size_t)blockIdx.x * TILE_SH;
    short* dst = Vimg + (size_t)blockIdx.x * TILE_SH;
    const int row = t >> 2, c16 = (t & 3) * 16;
    {
        float4 f0 = *reinterpret_cast<const float4*>(src + row * D + c16 + 0);
        float4 f1 = *reinterpret_cast<const float4*>(src + row * D + c16 + 4);
        float4 f2 = *reinterpret_cast<const float4*>(src + row * D + c16 + 8);
        float4 f3 = *reinterpret_cast<const float4*>(src + row * D + c16 + 12);
        tl[row][c16+0]=f0.x;  tl[row][c16+1]=f0.y;  tl[row][c16+2]=f0.z;  tl[row][c16+3]=f0.w;
        tl[row][c16+4]=f1.x;  tl[row][c16+5]=f1.y;  tl[row][c16+6]=f1.z;  tl[row][c16+7]=f1.w;
        tl[row][c16+8]=f2.x;  tl[row][c16+9]=f2.y;  tl[row][c16+10]=f2.z; tl[row][c16+11]=f2.w;
        tl[row][c16+12]=f3.x; tl[row][c16+13]=f3.y; tl[row][c16+14]=f3.z; tl[row][c16+15]=f3.w;
    }
    __syncthreads();
    const int d = t >> 2, k16 = (t & 3) * 16;
    const int swz = (d & 7) << 3;
    float vv[16];
#pragma unroll
    for (int j = 0; j < 16; ++j) vv[j] = tl[k16 + j][d];
    short8 a, b;
#pragma unroll
    for (int j = 0; j < 8; ++j) { a[j] = bfb(vv[j]); b[j] = bfb(vv[j + 8]); }
    *reinterpret_cast<short8*>(dst + d * 64 + (k16 ^ swz)) = a;
    *reinterpret_cast<short8*>(dst + d * 64 + ((k16 + 8) ^ swz)) = b;
}

// ---- main attention kernel
__global__ __launch_bounds__(256, 3)
void attn_img(const float* __restrict__ Q, const float* __restrict__ M,
              const short* __restrict__ Kimg, const short* __restrict__ Vimg,
              float* __restrict__ O)
{
    __shared__ short Kb[2][4096];     // 16 KB, pre-swizzled tile image
    __shared__ short Vb[2][4096];     // 16 KB
    __shared__ short Pt[4][32][64];   // 16 KB, per-wave P, XOR-swizzled

    const int tid  = threadIdx.x;
    const int w    = tid >> 6;
    const int lane = tid & 63;
    const int g    = lane >> 4;
    const int c    = lane & 15;
    const int swz8 = (c & 7) << 3;    // fragment-read swizzle (row%8 == c%8)

    const int bid = blockIdx.x;
    const int bh  = bid >> 4;
    const int qt  = bid & 15;
    const int qw  = qt * QBLK + w * 32;

    const size_t bhS = (size_t)bh * S;
    const size_t bhT = (size_t)bh * NKT;

    // ---- Q fragments (B operand): bQ[rt][kk], k = d = kk*32 + g*8 + i
    short8 bQ[2][2];
#pragma unroll
    for (int rt = 0; rt < 2; ++rt) {
        const float* qp = Q + (bhS + qw + rt * 16 + c) * D;
#pragma unroll
        for (int kk = 0; kk < 2; ++kk) {
            const float* q8 = qp + kk * 32 + g * 8;
            float4 a = *reinterpret_cast<const float4*>(q8);
            float4 b = *reinterpret_cast<const float4*>(q8 + 4);
            short8 r;
            r[0] = bfb(a.x * SCALE); r[1] = bfb(a.y * SCALE);
            r[2] = bfb(a.z * SCALE); r[3] = bfb(a.w * SCALE);
            r[4] = bfb(b.x * SCALE); r[5] = bfb(b.y * SCALE);
            r[6] = bfb(b.z * SCALE); r[7] = bfb(b.w * SCALE);
            bQ[rt][kk] = r;
        }
    }

    const float* mrow0 = M + (size_t)(qw + c) * S;
    const float* mrow1 = M + (size_t)(qw + 16 + c) * S;

    f32x4 acc[2][4] = {};
    float mR[2] = {-1e30f, -1e30f};
    float lR[2] = {0.f, 0.f};

    // stage tile kt into buffer buf (async, drained by next __syncthreads)
    auto stage = [&](int buf, int kt) {
        const short* ks = Kimg + (bhT + kt) * TILE_SH + w * 1024 + lane * 8;
        const short* vs = Vimg + (bhT + kt) * TILE_SH + w * 1024 + lane * 8;
#pragma unroll
        for (int i = 0; i < 2; ++i) {
            gload16(ks + i * 512, &Kb[buf][w * 1024 + i * 512]);
            gload16(vs + i * 512, &Vb[buf][w * 1024 + i * 512]);
        }
    };

    int cur = 0;
    stage(0, 0);
    __syncthreads();

    for (int kt = 0; kt < NKT; ++kt) {
        const int k0 = kt * KT;
        if (kt + 1 < NKT) stage(cur ^ 1, kt + 1);   // in flight across compute

        // ---- K fragments (A operand): row = key = n*16+c
        short8 aK[4][2];
#pragma unroll
        for (int n = 0; n < 4; ++n)
#pragma unroll
            for (int kk = 0; kk < 2; ++kk)
                aK[n][kk] = *reinterpret_cast<const short8*>(
                    &Kb[cur][(n * 16 + c) * 64 + ((kk * 32 + g * 8) ^ swz8)]);

        // ---- S^T = K · Q^T
        f32x4 s[2][4] = {};
        __builtin_amdgcn_s_setprio(1);
#pragma unroll
        for (int n = 0; n < 4; ++n)
#pragma unroll
            for (int rt = 0; rt < 2; ++rt)
#pragma unroll
                for (int kk = 0; kk < 2; ++kk)
                    s[rt][n] = __builtin_amdgcn_mfma_f32_16x16x32_bf16(
                        aK[n][kk], bQ[rt][kk], s[rt][n], 0, 0, 0);
        __builtin_amdgcn_s_setprio(0);

        // ---- online softmax (per-lane q-row), multiplicative mask
#pragma unroll
        for (int rt = 0; rt < 2; ++rt) {
            const float* mrow = rt ? mrow1 : mrow0;
            float sv[4][4];
            float smax = -1e30f;
#pragma unroll
            for (int n = 0; n < 4; ++n) {
                float4 mk = *reinterpret_cast<const float4*>(mrow + k0 + n * 16 + g * 4);
                sv[n][0] = s[rt][n][0] * mk.x;
                sv[n][1] = s[rt][n][1] * mk.y;
                sv[n][2] = s[rt][n][2] * mk.z;
                sv[n][3] = s[rt][n][3] * mk.w;
#pragma unroll
                for (int r = 0; r < 4; ++r) smax = fmaxf(smax, sv[n][r]);
            }
            smax = fmaxf(smax, __shfl_xor(smax, 16));
            smax = fmaxf(smax, __shfl_xor(smax, 32));

            if (__any(smax > mR[rt])) {   // exact: skipped only when fr==1
                const float mnew = fmaxf(mR[rt], smax);
                const float fr = exp2f(mR[rt] - mnew);
                mR[rt] = mnew;
                lR[rt] *= fr;
                const float frd0 = __shfl(fr, 4 * g + 0);
                const float frd1 = __shfl(fr, 4 * g + 1);
                const float frd2 = __shfl(fr, 4 * g + 2);
                const float frd3 = __shfl(fr, 4 * g + 3);
#pragma unroll
                for (int n = 0; n < 4; ++n) {
                    acc[rt][n][0] *= frd0; acc[rt][n][1] *= frd1;
                    acc[rt][n][2] *= frd2; acc[rt][n][3] *= frd3;
                }
            }

            float rs = 0.f;
            float p[4][4];
#pragma unroll
            for (int n = 0; n < 4; ++n)
#pragma unroll
                for (int r = 0; r < 4; ++r) {
                    p[n][r] = exp2f(sv[n][r] - mR[rt]);
                    rs += p[n][r];
                }
            rs += __shfl_xor(rs, 16);
            rs += __shfl_xor(rs, 32);
            lR[rt] += rs;

#pragma unroll
            for (int n = 0; n < 4; ++n) {
                short4v pk;
                pk[0] = bfb(p[n][0]); pk[1] = bfb(p[n][1]);
                pk[2] = bfb(p[n][2]); pk[3] = bfb(p[n][3]);
                *reinterpret_cast<short4v*>(
                    &Pt[w][rt * 16 + c][(n * 16 + g * 4) ^ swz8]) = pk;
            }
        }

        // ---- PV: A = P, B = V^T image (both swizzled reads)
        short8 bV[4][2];
#pragma unroll
        for (int n = 0; n < 4; ++n)
#pragma unroll
            for (int kk = 0; kk < 2; ++kk)
                bV[n][kk] = *reinterpret_cast<const short8*>(
                    &Vb[cur][(n * 16 + c) * 64 + ((kk * 32 + g * 8) ^ swz8)]);
        __builtin_amdgcn_s_setprio(1);
#pragma unroll
        for (int rt = 0; rt < 2; ++rt) {
#pragma unroll
            for (int kk = 0; kk < 2; ++kk) {
                short8 aP = *reinterpret_cast<const short8*>(
                    &Pt[w][rt * 16 + c][(kk * 32 + g * 8) ^ swz8]);
#pragma unroll
                for (int n = 0; n < 4; ++n)
                    acc[rt][n] = __builtin_amdgcn_mfma_f32_16x16x32_bf16(
                        aP, bV[n][kk], acc[rt][n], 0, 0, 0);
            }
        }
        __builtin_amdgcn_s_setprio(0);

        __syncthreads();   // drains gload_lds for next buffer; P reuse safe (per-wave)
        cur ^= 1;
    }

    // ---- epilogue
#pragma unroll
    for (int rt = 0; rt < 2; ++rt) {
        const float linv = 1.0f / lR[rt];
        float ld[4];
        ld[0] = __shfl(linv, 4 * g + 0);
        ld[1] = __shfl(linv, 4 * g + 1);
        ld[2] = __shfl(linv, 4 * g + 2);
        ld[3] = __shfl(linv, 4 * g + 3);
#pragma unroll
        for (int r = 0; r < 4; ++r) {
            float* op = O + (bhS + qw + rt * 16 + 4 * g + r) * D + c;
#pragma unroll
            for (int n = 0; n < 4; ++n) op[n * 16] = acc[rt][n][r] * ld[r];
        }
    }
}

// ---- fallback (ws too small): known-correct f32 kernel
constexpr int FQT = 256, FKT = 64, FSUB = 16;
__global__ __launch_bounds__(FQT)
void attn_f32(const float* __restrict__ Q, const float* __restrict__ K,
              const float* __restrict__ V, const float* __restrict__ M,
              float* __restrict__ O)
{
    __shared__ float Kt[FKT][D];
    __shared__ float Vt[FKT][D];
    const int tid = threadIdx.x;
    const int bh = blockIdx.x / (S / FQT);
    const int qrow = (blockIdx.x % (S / FQT)) * FQT + tid;
    const float* qp = Q + ((size_t)bh * S + qrow) * D;
    const float* mp = M + (size_t)qrow * S;
    const float* kb = K + (size_t)bh * S * D;
    const float* vb = V + (size_t)bh * S * D;
    float qv[D];
#pragma unroll
    for (int d = 0; d < D; d += 4) {
        float4 t = *reinterpret_cast<const float4*>(qp + d);
        qv[d] = t.x * 0.125f; qv[d+1] = t.y * 0.125f; qv[d+2] = t.z * 0.125f; qv[d+3] = t.w * 0.125f;
    }
    float acc[D];
#pragma unroll
    for (int d = 0; d < D; ++d) acc[d] = 0.f;
    float mrun = -1e30f, lrun = 0.f;
    for (int k0 = 0; k0 < S; k0 += FKT) {
        __syncthreads();
        const float4* ks = reinterpret_cast<const float4*>(kb + (size_t)k0 * D);
        const float4* vs = reinterpret_cast<const float4*>(vb + (size_t)k0 * D);
        float4* kd = reinterpret_cast<float4*>(&Kt[0][0]);
        float4* vd = reinterpret_cast<float4*>(&Vt[0][0]);
#pragma unroll
        for (int i = 0; i < (FKT * D / 4) / FQT; ++i) {
            kd[tid + FQT * i] = ks[tid + FQT * i];
            vd[tid + FQT * i] = vs[tid + FQT * i];
        }
        __syncthreads();
        for (int j0 = 0; j0 < FKT; j0 += FSUB) {
            float mk[FSUB];
#pragma unroll
            for (int i = 0; i < FSUB; i += 4) {
                float4 t = *reinterpret_cast<const float4*>(mp + k0 + j0 + i);
                mk[i] = t.x; mk[i+1] = t.y; mk[i+2] = t.z; mk[i+3] = t.w;
            }
            float sx[FSUB];
#pragma unroll
            for (int j = 0; j < FSUB; ++j) sx[j] = 0.f;
#pragma unroll
            for (int d = 0; d < D; d += 4)
#pragma unroll
                for (int j = 0; j < FSUB; ++j) {
                    float4 kv = *reinterpret_cast<const float4*>(&Kt[j0 + j][d]);
                    sx[j] = fmaf(qv[d], kv.x, sx[j]);
                    sx[j] = fmaf(qv[d+1], kv.y, sx[j]);
                    sx[j] = fmaf(qv[d+2], kv.z, sx[j]);
                    sx[j] = fmaf(qv[d+3], kv.w, sx[j]);
                }
            float cmax = -1e30f;
#pragma unroll
            for (int j = 0; j < FSUB; ++j) { sx[j] *= mk[j]; cmax = fmaxf(cmax, sx[j]); }
            if (cmax > mrun) {
                float r = __expf(mrun - cmax);
                mrun = cmax; lrun *= r;
#pragma unroll
                for (int d = 0; d < D; ++d) acc[d] *= r;
            }
#pragma unroll
            for (int j = 0; j < FSUB; ++j) {
                float p = __expf(sx[j] - mrun);
                lrun += p;
#pragma unroll
                for (int d = 0; d < D; d += 4) {
                    float4 vv = *reinterpret_cast<const float4*>(&Vt[j0 + j][d]);
                    acc[d] = fmaf(p, vv.x, acc[d]);
                    acc[d+1] = fmaf(p, vv.y, acc[d+1]);
                    acc[d+2] = fmaf(p, vv.z, acc[d+2]);
                    acc[d+3] = fmaf(p, vv.w, acc[d+3]);
                }
            }
        }
    }
    const float invl = 1.0f / lrun;
    float* op = O + ((size_t)bh * S + qrow) * D;
#pragma unroll
    for (int d = 0; d < D; d += 4) {
        float4 t;
        t.x = acc[d] * invl; t.y = acc[d+1] * invl; t.z = acc[d+2] * invl; t.w = acc[d+3] * invl;
        *reinterpret_cast<float4*>(op + d) = t;
    }
}

extern "C" void kernel_launch(void* const* d_in, const int* in_sizes, int n_in,
                              void* d_out, int out_size, void* d_ws, size_t ws_size,
                              hipStream_t stream) {
    const float* q = (const float*)d_in[0];
    const float* k = (const float*)d_in[1];
    const float* v = (const float*)d_in[2];
    const float* m = (const float*)d_in[3];
    float* out = (float*)d_out;
    if (ws_size >= WS_NEED) {
        short* kimg = (short*)d_ws;
        short* vimg = kimg + IMG_SH;
        conv_k<<<dim3(NBH * NKT), dim3(256), 0, stream>>>(k, kimg);
        conv_v<<<dim3(NBH * NKT), dim3(256), 0, stream>>>(v, vimg);
        attn_img<<<dim3(NBH * NQT), dim3(256), 0, stream>>>(q, m, kimg, vimg, out);
    } else {
        attn_f32<<<dim3(NBH * (S / FQT)), dim3(256), 0, stream>>>(q, k, v, m, out);
    }
}

// Round 5
// 206.704 us; speedup vs baseline: 5.4380x; 1.0131x over previous
//
#include <hip/hip_runtime.h>
#include <hip/hip_bf16.h>

// R5 = R4 structure + __expf (fast exp intrinsic, not exp2f libcall) + merged
// conv prepass. bf16 MFMA flash attention, pre-swizzled K/V tile images in ws.
// B=4 H=16 S=2048 D=64, f32 in/out, multiplicative mask.

typedef __attribute__((ext_vector_type(4))) float  f32x4;
typedef __attribute__((ext_vector_type(8))) short  short8;
typedef __attribute__((ext_vector_type(4))) short  short4v;

constexpr int S = 2048, D = 64;
constexpr int NBH = 64;
constexpr int QBLK = 128, KT = 64;
constexpr int NQT = S / QBLK;      // 16
constexpr int NKT = S / KT;        // 32
constexpr float SCALE = 0.125f;    // 1/T (natural units; __expf does log2e internally)
constexpr size_t TILE_SH = (size_t)KT * D;                 // 4096 shorts per tile image
constexpr size_t IMG_SH  = (size_t)NBH * NKT * TILE_SH;
constexpr size_t WS_NEED = 2 * IMG_SH * sizeof(short);     // 33.55 MB

__device__ inline unsigned short bfb(float x) {
    union { __hip_bfloat16 h; unsigned short u; } cv;
    cv.h = __float2bfloat16(x);
    return cv.u;
}

__device__ inline void gload16(const short* g, short* l) {
    auto gp = (const __attribute__((address_space(1))) int*)g;
    auto lp = (__attribute__((address_space(3))) int*)l;
    __builtin_amdgcn_global_load_lds(gp, lp, 16, 0, 0);
}

// ---- merged pre-pass.
// blocks [0, NBH*NKT):       K -> swizzled bf16 tile image [key][d^8*(key&7)]
// blocks [NBH*NKT, 2*NBH*NKT): V -> transposed swizzled image [d][key^8*(d&7)]
__global__ __launch_bounds__(256)
void conv_kv(const float* __restrict__ K, const float* __restrict__ V,
             short* __restrict__ Kimg, short* __restrict__ Vimg) {
    const int t = threadIdx.x;
    const int nt = NBH * NKT;
    if (blockIdx.x < nt) {
        const float* src = K + (size_t)blockIdx.x * TILE_SH;
        short* dst = Kimg + (size_t)blockIdx.x * TILE_SH;
        const int row = t >> 2, c16 = (t & 3) * 16;
        const int swz = (row & 7) << 3;
        float4 f0 = *reinterpret_cast<const float4*>(src + row * D + c16 + 0);
        float4 f1 = *reinterpret_cast<const float4*>(src + row * D + c16 + 4);
        float4 f2 = *reinterpret_cast<const float4*>(src + row * D + c16 + 8);
        float4 f3 = *reinterpret_cast<const float4*>(src + row * D + c16 + 12);
        short8 a, b;
        a[0]=bfb(f0.x); a[1]=bfb(f0.y); a[2]=bfb(f0.z); a[3]=bfb(f0.w);
        a[4]=bfb(f1.x); a[5]=bfb(f1.y); a[6]=bfb(f1.z); a[7]=bfb(f1.w);
        b[0]=bfb(f2.x); b[1]=bfb(f2.y); b[2]=bfb(f2.z); b[3]=bfb(f2.w);
        b[4]=bfb(f3.x); b[5]=bfb(f3.y); b[6]=bfb(f3.z); b[7]=bfb(f3.w);
        *reinterpret_cast<short8*>(dst + row * 64 + (c16 ^ swz)) = a;
        *reinterpret_cast<short8*>(dst + row * 64 + ((c16 + 8) ^ swz)) = b;
    } else {
        __shared__ float tl[64][65];
        const int blk = blockIdx.x - nt;
        const float* src = V + (size_t)blk * TILE_SH;
        short* dst = Vimg + (size_t)blk * TILE_SH;
        const int row = t >> 2, c16 = (t & 3) * 16;
        {
            float4 f0 = *reinterpret_cast<const float4*>(src + row * D + c16 + 0);
            float4 f1 = *reinterpret_cast<const float4*>(src + row * D + c16 + 4);
            float4 f2 = *reinterpret_cast<const float4*>(src + row * D + c16 + 8);
            float4 f3 = *reinterpret_cast<const float4*>(src + row * D + c16 + 12);
            tl[row][c16+0]=f0.x;  tl[row][c16+1]=f0.y;  tl[row][c16+2]=f0.z;  tl[row][c16+3]=f0.w;
            tl[row][c16+4]=f1.x;  tl[row][c16+5]=f1.y;  tl[row][c16+6]=f1.z;  tl[row][c16+7]=f1.w;
            tl[row][c16+8]=f2.x;  tl[row][c16+9]=f2.y;  tl[row][c16+10]=f2.z; tl[row][c16+11]=f2.w;
            tl[row][c16+12]=f3.x; tl[row][c16+13]=f3.y; tl[row][c16+14]=f3.z; tl[row][c16+15]=f3.w;
        }
        __syncthreads();
        const int d = t >> 2, k16 = (t & 3) * 16;
        const int swz = (d & 7) << 3;
        float vv[16];
#pragma unroll
        for (int j = 0; j < 16; ++j) vv[j] = tl[k16 + j][d];
        short8 a, b;
#pragma unroll
        for (int j = 0; j < 8; ++j) { a[j] = bfb(vv[j]); b[j] = bfb(vv[j + 8]); }
        *reinterpret_cast<short8*>(dst + d * 64 + (k16 ^ swz)) = a;
        *reinterpret_cast<short8*>(dst + d * 64 + ((k16 + 8) ^ swz)) = b;
    }
}

// ---- main attention kernel
__global__ __launch_bounds__(256, 3)
void attn_img(const float* __restrict__ Q, const float* __restrict__ M,
              const short* __restrict__ Kimg, const short* __restrict__ Vimg,
              float* __restrict__ O)
{
    __shared__ short Kb[2][4096];     // 16 KB, pre-swizzled tile image
    __shared__ short Vb[2][4096];     // 16 KB
    __shared__ short Pt[4][32][64];   // 16 KB, per-wave P, XOR-swizzled

    const int tid  = threadIdx.x;
    const int w    = tid >> 6;
    const int lane = tid & 63;
    const int g    = lane >> 4;
    const int c    = lane & 15;
    const int swz8 = (c & 7) << 3;    // fragment-read swizzle (row%8 == c%8)

    const int bid = blockIdx.x;
    const int bh  = bid >> 4;
    const int qt  = bid & 15;
    const int qw  = qt * QBLK + w * 32;

    const size_t bhS = (size_t)bh * S;
    const size_t bhT = (size_t)bh * NKT;

    // ---- Q fragments (B operand): bQ[rt][kk], k = d = kk*32 + g*8 + i
    short8 bQ[2][2];
#pragma unroll
    for (int rt = 0; rt < 2; ++rt) {
        const float* qp = Q + (bhS + qw + rt * 16 + c) * D;
#pragma unroll
        for (int kk = 0; kk < 2; ++kk) {
            const float* q8 = qp + kk * 32 + g * 8;
            float4 a = *reinterpret_cast<const float4*>(q8);
            float4 b = *reinterpret_cast<const float4*>(q8 + 4);
            short8 r;
            r[0] = bfb(a.x * SCALE); r[1] = bfb(a.y * SCALE);
            r[2] = bfb(a.z * SCALE); r[3] = bfb(a.w * SCALE);
            r[4] = bfb(b.x * SCALE); r[5] = bfb(b.y * SCALE);
            r[6] = bfb(b.z * SCALE); r[7] = bfb(b.w * SCALE);
            bQ[rt][kk] = r;
        }
    }

    const float* mrow0 = M + (size_t)(qw + c) * S;
    const float* mrow1 = M + (size_t)(qw + 16 + c) * S;

    f32x4 acc[2][4] = {};
    float mR[2] = {-1e30f, -1e30f};
    float lR[2] = {0.f, 0.f};

    auto stage = [&](int buf, int kt) {
        const short* ks = Kimg + (bhT + kt) * TILE_SH + w * 1024 + lane * 8;
        const short* vs = Vimg + (bhT + kt) * TILE_SH + w * 1024 + lane * 8;
#pragma unroll
        for (int i = 0; i < 2; ++i) {
            gload16(ks + i * 512, &Kb[buf][w * 1024 + i * 512]);
            gload16(vs + i * 512, &Vb[buf][w * 1024 + i * 512]);
        }
    };

    int cur = 0;
    stage(0, 0);
    __syncthreads();

    for (int kt = 0; kt < NKT; ++kt) {
        const int k0 = kt * KT;
        if (kt + 1 < NKT) stage(cur ^ 1, kt + 1);

        // ---- K fragments (A operand): row = key = n*16+c
        short8 aK[4][2];
#pragma unroll
        for (int n = 0; n < 4; ++n)
#pragma unroll
            for (int kk = 0; kk < 2; ++kk)
                aK[n][kk] = *reinterpret_cast<const short8*>(
                    &Kb[cur][(n * 16 + c) * 64 + ((kk * 32 + g * 8) ^ swz8)]);

        // ---- S^T = K · Q^T
        f32x4 s[2][4] = {};
        __builtin_amdgcn_s_setprio(1);
#pragma unroll
        for (int n = 0; n < 4; ++n)
#pragma unroll
            for (int rt = 0; rt < 2; ++rt)
#pragma unroll
                for (int kk = 0; kk < 2; ++kk)
                    s[rt][n] = __builtin_amdgcn_mfma_f32_16x16x32_bf16(
                        aK[n][kk], bQ[rt][kk], s[rt][n], 0, 0, 0);
        __builtin_amdgcn_s_setprio(0);

        // ---- online softmax (per-lane q-row), multiplicative mask
#pragma unroll
        for (int rt = 0; rt < 2; ++rt) {
            const float* mrow = rt ? mrow1 : mrow0;
            float sv[4][4];
            float smax = -1e30f;
#pragma unroll
            for (int n = 0; n < 4; ++n) {
                float4 mk = *reinterpret_cast<const float4*>(mrow + k0 + n * 16 + g * 4);
                sv[n][0] = s[rt][n][0] * mk.x;
                sv[n][1] = s[rt][n][1] * mk.y;
                sv[n][2] = s[rt][n][2] * mk.z;
                sv[n][3] = s[rt][n][3] * mk.w;
#pragma unroll
                for (int r = 0; r < 4; ++r) smax = fmaxf(smax, sv[n][r]);
            }
            smax = fmaxf(smax, __shfl_xor(smax, 16));
            smax = fmaxf(smax, __shfl_xor(smax, 32));

            if (__any(smax > mR[rt])) {   // skipped once running max stabilizes
                const float mnew = fmaxf(mR[rt], smax);
                const float fr = __expf(mR[rt] - mnew);
                mR[rt] = mnew;
                lR[rt] *= fr;
                const float frd0 = __shfl(fr, 4 * g + 0);
                const float frd1 = __shfl(fr, 4 * g + 1);
                const float frd2 = __shfl(fr, 4 * g + 2);
                const float frd3 = __shfl(fr, 4 * g + 3);
#pragma unroll
                for (int n = 0; n < 4; ++n) {
                    acc[rt][n][0] *= frd0; acc[rt][n][1] *= frd1;
                    acc[rt][n][2] *= frd2; acc[rt][n][3] *= frd3;
                }
            }

            float rs = 0.f;
            float p[4][4];
#pragma unroll
            for (int n = 0; n < 4; ++n)
#pragma unroll
                for (int r = 0; r < 4; ++r) {
                    p[n][r] = __expf(sv[n][r] - mR[rt]);
                    rs += p[n][r];
                }
            rs += __shfl_xor(rs, 16);
            rs += __shfl_xor(rs, 32);
            lR[rt] += rs;

#pragma unroll
            for (int n = 0; n < 4; ++n) {
                short4v pk;
                pk[0] = bfb(p[n][0]); pk[1] = bfb(p[n][1]);
                pk[2] = bfb(p[n][2]); pk[3] = bfb(p[n][3]);
                *reinterpret_cast<short4v*>(
                    &Pt[w][rt * 16 + c][(n * 16 + g * 4) ^ swz8]) = pk;
            }
        }

        // ---- PV: A = P, B = V^T image (both swizzled reads)
        short8 bV[4][2];
#pragma unroll
        for (int n = 0; n < 4; ++n)
#pragma unroll
            for (int kk = 0; kk < 2; ++kk)
                bV[n][kk] = *reinterpret_cast<const short8*>(
                    &Vb[cur][(n * 16 + c) * 64 + ((kk * 32 + g * 8) ^ swz8)]);
        __builtin_amdgcn_s_setprio(1);
#pragma unroll
        for (int rt = 0; rt < 2; ++rt) {
#pragma unroll
            for (int kk = 0; kk < 2; ++kk) {
                short8 aP = *reinterpret_cast<const short8*>(
                    &Pt[w][rt * 16 + c][(kk * 32 + g * 8) ^ swz8]);
#pragma unroll
                for (int n = 0; n < 4; ++n)
                    acc[rt][n] = __builtin_amdgcn_mfma_f32_16x16x32_bf16(
                        aP, bV[n][kk], acc[rt][n], 0, 0, 0);
            }
        }
        __builtin_amdgcn_s_setprio(0);

        __syncthreads();   // drains gload_lds for next buffer
        cur ^= 1;
    }

    // ---- epilogue
#pragma unroll
    for (int rt = 0; rt < 2; ++rt) {
        const float linv = 1.0f / lR[rt];
        float ld[4];
        ld[0] = __shfl(linv, 4 * g + 0);
        ld[1] = __shfl(linv, 4 * g + 1);
        ld[2] = __shfl(linv, 4 * g + 2);
        ld[3] = __shfl(linv, 4 * g + 3);
#pragma unroll
        for (int r = 0; r < 4; ++r) {
            float* op = O + (bhS + qw + rt * 16 + 4 * g + r) * D + c;
#pragma unroll
            for (int n = 0; n < 4; ++n) op[n * 16] = acc[rt][n][r] * ld[r];
        }
    }
}

// ---- fallback (ws too small): known-correct f32 kernel
constexpr int FQT = 256, FKT = 64, FSUB = 16;
__global__ __launch_bounds__(FQT)
void attn_f32(const float* __restrict__ Q, const float* __restrict__ K,
              const float* __restrict__ V, const float* __restrict__ M,
              float* __restrict__ O)
{
    __shared__ float Kt[FKT][D];
    __shared__ float Vt[FKT][D];
    const int tid = threadIdx.x;
    const int bh = blockIdx.x / (S / FQT);
    const int qrow = (blockIdx.x % (S / FQT)) * FQT + tid;
    const float* qp = Q + ((size_t)bh * S + qrow) * D;
    const float* mp = M + (size_t)qrow * S;
    const float* kb = K + (size_t)bh * S * D;
    const float* vb = V + (size_t)bh * S * D;
    float qv[D];
#pragma unroll
    for (int d = 0; d < D; d += 4) {
        float4 t = *reinterpret_cast<const float4*>(qp + d);
        qv[d] = t.x * 0.125f; qv[d+1] = t.y * 0.125f; qv[d+2] = t.z * 0.125f; qv[d+3] = t.w * 0.125f;
    }
    float acc[D];
#pragma unroll
    for (int d = 0; d < D; ++d) acc[d] = 0.f;
    float mrun = -1e30f, lrun = 0.f;
    for (int k0 = 0; k0 < S; k0 += FKT) {
        __syncthreads();
        const float4* ks = reinterpret_cast<const float4*>(kb + (size_t)k0 * D);
        const float4* vs = reinterpret_cast<const float4*>(vb + (size_t)k0 * D);
        float4* kd = reinterpret_cast<float4*>(&Kt[0][0]);
        float4* vd = reinterpret_cast<float4*>(&Vt[0][0]);
#pragma unroll
        for (int i = 0; i < (FKT * D / 4) / FQT; ++i) {
            kd[tid + FQT * i] = ks[tid + FQT * i];
            vd[tid + FQT * i] = vs[tid + FQT * i];
        }
        __syncthreads();
        for (int j0 = 0; j0 < FKT; j0 += FSUB) {
            float mk[FSUB];
#pragma unroll
            for (int i = 0; i < FSUB; i += 4) {
                float4 t = *reinterpret_cast<const float4*>(mp + k0 + j0 + i);
                mk[i] = t.x; mk[i+1] = t.y; mk[i+2] = t.z; mk[i+3] = t.w;
            }
            float sx[FSUB];
#pragma unroll
            for (int j = 0; j < FSUB; ++j) sx[j] = 0.f;
#pragma unroll
            for (int d = 0; d < D; d += 4)
#pragma unroll
                for (int j = 0; j < FSUB; ++j) {
                    float4 kv = *reinterpret_cast<const float4*>(&Kt[j0 + j][d]);
                    sx[j] = fmaf(qv[d], kv.x, sx[j]);
                    sx[j] = fmaf(qv[d+1], kv.y, sx[j]);
                    sx[j] = fmaf(qv[d+2], kv.z, sx[j]);
                    sx[j] = fmaf(qv[d+3], kv.w, sx[j]);
                }
            float cmax = -1e30f;
#pragma unroll
            for (int j = 0; j < FSUB; ++j) { sx[j] *= mk[j]; cmax = fmaxf(cmax, sx[j]); }
            if (cmax > mrun) {
                float r = __expf(mrun - cmax);
                mrun = cmax; lrun *= r;
#pragma unroll
                for (int d = 0; d < D; ++d) acc[d] *= r;
            }
#pragma unroll
            for (int j = 0; j < FSUB; ++j) {
                float p = __expf(sx[j] - mrun);
                lrun += p;
#pragma unroll
                for (int d = 0; d < D; d += 4) {
                    float4 vv = *reinterpret_cast<const float4*>(&Vt[j0 + j][d]);
                    acc[d] = fmaf(p, vv.x, acc[d]);
                    acc[d+1] = fmaf(p, vv.y, acc[d+1]);
                    acc[d+2] = fmaf(p, vv.z, acc[d+2]);
                    acc[d+3] = fmaf(p, vv.w, acc[d+3]);
                }
            }
        }
    }
    const float invl = 1.0f / lrun;
    float* op = O + ((size_t)bh * S + qrow) * D;
#pragma unroll
    for (int d = 0; d < D; d += 4) {
        float4 t;
        t.x = acc[d] * invl; t.y = acc[d+1] * invl; t.z = acc[d+2] * invl; t.w = acc[d+3] * invl;
        *reinterpret_cast<float4*>(op + d) = t;
    }
}

extern "C" void kernel_launch(void* const* d_in, const int* in_sizes, int n_in,
                              void* d_out, int out_size, void* d_ws, size_t ws_size,
                              hipStream_t stream) {
    const float* q = (const float*)d_in[0];
    const float* k = (const float*)d_in[1];
    const float* v = (const float*)d_in[2];
    const float* m = (const float*)d_in[3];
    float* out = (float*)d_out;
    if (ws_size >= WS_NEED) {
        short* kimg = (short*)d_ws;
        short* vimg = kimg + IMG_SH;
        conv_kv<<<dim3(2 * NBH * NKT), dim3(256), 0, stream>>>(k, v, kimg, vimg);
        attn_img<<<dim3(NBH * NQT), dim3(256), 0, stream>>>(q, m, kimg, vimg, out);
    } else {
        attn_f32<<<dim3(NBH * (S / FQT)), dim3(256), 0, stream>>>(q, k, v, m, out);
    }
}

// Round 6
// 165.834 us; speedup vs baseline: 6.7782x; 1.2464x over previous
//
#include <hip/hip_runtime.h>
#include <hip/hip_bf16.h>

// R6: fixed-max softmax (scores provably bounded -> m=0, exact), zero
// cross-lane ops in inner loop; QBLK=256 -> grid=512 = exactly 2 blocks/CU.
// bf16 MFMA flash attention, pre-swizzled K/V tile images in ws.
// B=4 H=16 S=2048 D=64, f32 in/out, multiplicative mask.

typedef __attribute__((ext_vector_type(4))) float  f32x4;
typedef __attribute__((ext_vector_type(8))) short  short8;
typedef __attribute__((ext_vector_type(4))) short  short4v;

constexpr int S = 2048, D = 64;
constexpr int NBH = 64;
constexpr int QBLK = 256, KT = 64;
constexpr int NQT = S / QBLK;      // 8
constexpr int NKT = S / KT;        // 32
constexpr float SCALE = 0.125f;    // 1/T
constexpr size_t TILE_SH = (size_t)KT * D;                 // 4096 shorts per tile image
constexpr size_t IMG_SH  = (size_t)NBH * NKT * TILE_SH;
constexpr size_t WS_NEED = 2 * IMG_SH * sizeof(short);     // 33.55 MB

__device__ inline unsigned short bfb(float x) {
    union { __hip_bfloat16 h; unsigned short u; } cv;
    cv.h = __float2bfloat16(x);
    return cv.u;
}

__device__ inline void gload16(const short* g, short* l) {
    auto gp = (const __attribute__((address_space(1))) int*)g;
    auto lp = (__attribute__((address_space(3))) int*)l;
    __builtin_amdgcn_global_load_lds(gp, lp, 16, 0, 0);
}

// ---- merged pre-pass.
// blocks [0, NBH*NKT):        K -> swizzled bf16 tile image [key][d^8*(key&7)]
// blocks [NBH*NKT, 2*NBH*NKT): V -> transposed swizzled image [d][key^8*(d&7)]
__global__ __launch_bounds__(256)
void conv_kv(const float* __restrict__ K, const float* __restrict__ V,
             short* __restrict__ Kimg, short* __restrict__ Vimg) {
    const int t = threadIdx.x;
    const int nt = NBH * NKT;
    if (blockIdx.x < nt) {
        const float* src = K + (size_t)blockIdx.x * TILE_SH;
        short* dst = Kimg + (size_t)blockIdx.x * TILE_SH;
        const int row = t >> 2, c16 = (t & 3) * 16;
        const int swz = (row & 7) << 3;
        float4 f0 = *reinterpret_cast<const float4*>(src + row * D + c16 + 0);
        float4 f1 = *reinterpret_cast<const float4*>(src + row * D + c16 + 4);
        float4 f2 = *reinterpret_cast<const float4*>(src + row * D + c16 + 8);
        float4 f3 = *reinterpret_cast<const float4*>(src + row * D + c16 + 12);
        short8 a, b;
        a[0]=bfb(f0.x); a[1]=bfb(f0.y); a[2]=bfb(f0.z); a[3]=bfb(f0.w);
        a[4]=bfb(f1.x); a[5]=bfb(f1.y); a[6]=bfb(f1.z); a[7]=bfb(f1.w);
        b[0]=bfb(f2.x); b[1]=bfb(f2.y); b[2]=bfb(f2.z); b[3]=bfb(f2.w);
        b[4]=bfb(f3.x); b[5]=bfb(f3.y); b[6]=bfb(f3.z); b[7]=bfb(f3.w);
        *reinterpret_cast<short8*>(dst + row * 64 + (c16 ^ swz)) = a;
        *reinterpret_cast<short8*>(dst + row * 64 + ((c16 + 8) ^ swz)) = b;
    } else {
        __shared__ float tl[64][65];
        const int blk = blockIdx.x - nt;
        const float* src = V + (size_t)blk * TILE_SH;
        short* dst = Vimg + (size_t)blk * TILE_SH;
        const int row = t >> 2, c16 = (t & 3) * 16;
        {
            float4 f0 = *reinterpret_cast<const float4*>(src + row * D + c16 + 0);
            float4 f1 = *reinterpret_cast<const float4*>(src + row * D + c16 + 4);
            float4 f2 = *reinterpret_cast<const float4*>(src + row * D + c16 + 8);
            float4 f3 = *reinterpret_cast<const float4*>(src + row * D + c16 + 12);
            tl[row][c16+0]=f0.x;  tl[row][c16+1]=f0.y;  tl[row][c16+2]=f0.z;  tl[row][c16+3]=f0.w;
            tl[row][c16+4]=f1.x;  tl[row][c16+5]=f1.y;  tl[row][c16+6]=f1.z;  tl[row][c16+7]=f1.w;
            tl[row][c16+8]=f2.x;  tl[row][c16+9]=f2.y;  tl[row][c16+10]=f2.z; tl[row][c16+11]=f2.w;
            tl[row][c16+12]=f3.x; tl[row][c16+13]=f3.y; tl[row][c16+14]=f3.z; tl[row][c16+15]=f3.w;
        }
        __syncthreads();
        const int d = t >> 2, k16 = (t & 3) * 16;
        const int swz = (d & 7) << 3;
        float vv[16];
#pragma unroll
        for (int j = 0; j < 16; ++j) vv[j] = tl[k16 + j][d];
        short8 a, b;
#pragma unroll
        for (int j = 0; j < 8; ++j) { a[j] = bfb(vv[j]); b[j] = bfb(vv[j + 8]); }
        *reinterpret_cast<short8*>(dst + d * 64 + (k16 ^ swz)) = a;
        *reinterpret_cast<short8*>(dst + d * 64 + ((k16 + 8) ^ swz)) = b;
    }
}

// ---- main attention kernel: 4 waves x 64 q-rows each
__global__ __launch_bounds__(256, 2)
void attn_img(const float* __restrict__ Q, const float* __restrict__ M,
              const short* __restrict__ Kimg, const short* __restrict__ Vimg,
              float* __restrict__ O)
{
    __shared__ short Kb[2][4096];     // 16 KB, pre-swizzled tile image
    __shared__ short Vb[2][4096];     // 16 KB
    __shared__ short Pt[4][64][64];   // 32 KB, per-wave P, XOR-swizzled

    const int tid  = threadIdx.x;
    const int w    = tid >> 6;
    const int lane = tid & 63;
    const int g    = lane >> 4;
    const int c    = lane & 15;
    const int swz8 = (c & 7) << 3;    // fragment-read swizzle (row%8 == c%8)

    const int bid = blockIdx.x;
    const int bh  = bid >> 3;         // 0..63
    const int qt  = bid & 7;
    const int qw  = qt * QBLK + w * 64;   // this wave's first q-row (64 rows)

    const size_t bhS = (size_t)bh * S;
    const size_t bhT = (size_t)bh * NKT;

    // ---- Q fragments (B operand): bQ[rt][kk], row = qw+rt*16+c, k = d
    short8 bQ[4][2];
#pragma unroll
    for (int rt = 0; rt < 4; ++rt) {
        const float* qp = Q + (bhS + qw + rt * 16 + c) * D;
#pragma unroll
        for (int kk = 0; kk < 2; ++kk) {
            const float* q8 = qp + kk * 32 + g * 8;
            float4 a = *reinterpret_cast<const float4*>(q8);
            float4 b = *reinterpret_cast<const float4*>(q8 + 4);
            short8 r;
            r[0] = bfb(a.x * SCALE); r[1] = bfb(a.y * SCALE);
            r[2] = bfb(a.z * SCALE); r[3] = bfb(a.w * SCALE);
            r[4] = bfb(b.x * SCALE); r[5] = bfb(b.y * SCALE);
            r[6] = bfb(b.z * SCALE); r[7] = bfb(b.w * SCALE);
            bQ[rt][kk] = r;
        }
    }

    const float* mrow[4];
#pragma unroll
    for (int rt = 0; rt < 4; ++rt)
        mrow[rt] = M + (size_t)(qw + rt * 16 + c) * S;

    f32x4 acc[4][4] = {};             // [rt][d-ntile]; reg r -> qrow 4g+r, col c -> d
    float lR[4] = {0.f, 0.f, 0.f, 0.f};  // per-lane PARTIAL denominator (this lane's keys)

    auto stage = [&](int buf, int kt) {
        const short* ks = Kimg + (bhT + kt) * TILE_SH + w * 1024 + lane * 8;
        const short* vs = Vimg + (bhT + kt) * TILE_SH + w * 1024 + lane * 8;
#pragma unroll
        for (int i = 0; i < 2; ++i) {
            gload16(ks + i * 512, &Kb[buf][w * 1024 + i * 512]);
            gload16(vs + i * 512, &Vb[buf][w * 1024 + i * 512]);
        }
    };

    int cur = 0;
    stage(0, 0);
    __syncthreads();

    for (int kt = 0; kt < NKT; ++kt) {
        const int k0 = kt * KT;
        if (kt + 1 < NKT) stage(cur ^ 1, kt + 1);   // in flight across compute

        // ---- K fragments (A operand): row = key = n*16+c
        short8 aK[4][2];
#pragma unroll
        for (int n = 0; n < 4; ++n)
#pragma unroll
            for (int kk = 0; kk < 2; ++kk)
                aK[n][kk] = *reinterpret_cast<const short8*>(
                    &Kb[cur][(n * 16 + c) * 64 + ((kk * 32 + g * 8) ^ swz8)]);

        // ---- per rowtile: QK^T -> mask -> exp (fixed max 0) -> P to LDS
#pragma unroll
        for (int rt = 0; rt < 4; ++rt) {
            f32x4 s[4] = {};
            __builtin_amdgcn_s_setprio(1);
#pragma unroll
            for (int n = 0; n < 4; ++n)
#pragma unroll
                for (int kk = 0; kk < 2; ++kk)
                    s[n] = __builtin_amdgcn_mfma_f32_16x16x32_bf16(
                        aK[n][kk], bQ[rt][kk], s[n], 0, 0, 0);
            __builtin_amdgcn_s_setprio(0);

            float lp = 0.f;
#pragma unroll
            for (int n = 0; n < 4; ++n) {
                float4 mk = *reinterpret_cast<const float4*>(mrow[rt] + k0 + n * 16 + g * 4);
                float e0 = __expf(s[n][0] * mk.x);
                float e1 = __expf(s[n][1] * mk.y);
                float e2 = __expf(s[n][2] * mk.z);
                float e3 = __expf(s[n][3] * mk.w);
                lp += (e0 + e1) + (e2 + e3);
                short4v pk;
                pk[0] = bfb(e0); pk[1] = bfb(e1); pk[2] = bfb(e2); pk[3] = bfb(e3);
                *reinterpret_cast<short4v*>(
                    &Pt[w][rt * 16 + c][(n * 16 + g * 4) ^ swz8]) = pk;
            }
            lR[rt] += lp;
        }

        // ---- PV: A = P, B = V^T image (both swizzled reads)
        short8 bV[4][2];
#pragma unroll
        for (int n = 0; n < 4; ++n)
#pragma unroll
            for (int kk = 0; kk < 2; ++kk)
                bV[n][kk] = *reinterpret_cast<const short8*>(
                    &Vb[cur][(n * 16 + c) * 64 + ((kk * 32 + g * 8) ^ swz8)]);
        __builtin_amdgcn_s_setprio(1);
#pragma unroll
        for (int rt = 0; rt < 4; ++rt) {
#pragma unroll
            for (int kk = 0; kk < 2; ++kk) {
                short8 aP = *reinterpret_cast<const short8*>(
                    &Pt[w][rt * 16 + c][(kk * 32 + g * 8) ^ swz8]);
#pragma unroll
                for (int n = 0; n < 4; ++n)
                    acc[rt][n] = __builtin_amdgcn_mfma_f32_16x16x32_bf16(
                        aP, bV[n][kk], acc[rt][n], 0, 0, 0);
            }
        }
        __builtin_amdgcn_s_setprio(0);

        __syncthreads();   // drains gload_lds for next buffer
        cur ^= 1;
    }

    // ---- epilogue: single cross-lane reduce of denominator, normalize, store
#pragma unroll
    for (int rt = 0; rt < 4; ++rt) {
        float l = lR[rt];
        l += __shfl_xor(l, 16);
        l += __shfl_xor(l, 32);        // now l = full denom for q-row (rt,c)
        const float linv = 1.0f / l;
        float ld[4];
        ld[0] = __shfl(linv, 4 * g + 0);
        ld[1] = __shfl(linv, 4 * g + 1);
        ld[2] = __shfl(linv, 4 * g + 2);
        ld[3] = __shfl(linv, 4 * g + 3);
#pragma unroll
        for (int r = 0; r < 4; ++r) {
            float* op = O + (bhS + qw + rt * 16 + 4 * g + r) * D + c;
#pragma unroll
            for (int n = 0; n < 4; ++n) op[n * 16] = acc[rt][n][r] * ld[r];
        }
    }
}

// ---- fallback (ws too small): known-correct f32 kernel
constexpr int FQT = 256, FKT = 64, FSUB = 16;
__global__ __launch_bounds__(FQT)
void attn_f32(const float* __restrict__ Q, const float* __restrict__ K,
              const float* __restrict__ V, const float* __restrict__ M,
              float* __restrict__ O)
{
    __shared__ float Kt[FKT][D];
    __shared__ float Vt[FKT][D];
    const int tid = threadIdx.x;
    const int bh = blockIdx.x / (S / FQT);
    const int qrow = (blockIdx.x % (S / FQT)) * FQT + tid;
    const float* qp = Q + ((size_t)bh * S + qrow) * D;
    const float* mp = M + (size_t)qrow * S;
    const float* kb = K + (size_t)bh * S * D;
    const float* vb = V + (size_t)bh * S * D;
    float qv[D];
#pragma unroll
    for (int d = 0; d < D; d += 4) {
        float4 t = *reinterpret_cast<const float4*>(qp + d);
        qv[d] = t.x * 0.125f; qv[d+1] = t.y * 0.125f; qv[d+2] = t.z * 0.125f; qv[d+3] = t.w * 0.125f;
    }
    float acc[D];
#pragma unroll
    for (int d = 0; d < D; ++d) acc[d] = 0.f;
    float mrun = -1e30f, lrun = 0.f;
    for (int k0 = 0; k0 < S; k0 += FKT) {
        __syncthreads();
        const float4* ks = reinterpret_cast<const float4*>(kb + (size_t)k0 * D);
        const float4* vs = reinterpret_cast<const float4*>(vb + (size_t)k0 * D);
        float4* kd = reinterpret_cast<float4*>(&Kt[0][0]);
        float4* vd = reinterpret_cast<float4*>(&Vt[0][0]);
#pragma unroll
        for (int i = 0; i < (FKT * D / 4) / FQT; ++i) {
            kd[tid + FQT * i] = ks[tid + FQT * i];
            vd[tid + FQT * i] = vs[tid + FQT * i];
        }
        __syncthreads();
        for (int j0 = 0; j0 < FKT; j0 += FSUB) {
            float mk[FSUB];
#pragma unroll
            for (int i = 0; i < FSUB; i += 4) {
                float4 t = *reinterpret_cast<const float4*>(mp + k0 + j0 + i);
                mk[i] = t.x; mk[i+1] = t.y; mk[i+2] = t.z; mk[i+3] = t.w;
            }
            float sx[FSUB];
#pragma unroll
            for (int j = 0; j < FSUB; ++j) sx[j] = 0.f;
#pragma unroll
            for (int d = 0; d < D; d += 4)
#pragma unroll
                for (int j = 0; j < FSUB; ++j) {
                    float4 kv = *reinterpret_cast<const float4*>(&Kt[j0 + j][d]);
                    sx[j] = fmaf(qv[d], kv.x, sx[j]);
                    sx[j] = fmaf(qv[d+1], kv.y, sx[j]);
                    sx[j] = fmaf(qv[d+2], kv.z, sx[j]);
                    sx[j] = fmaf(qv[d+3], kv.w, sx[j]);
                }
            float cmax = -1e30f;
#pragma unroll
            for (int j = 0; j < FSUB; ++j) { sx[j] *= mk[j]; cmax = fmaxf(cmax, sx[j]); }
            if (cmax > mrun) {
                float r = __expf(mrun - cmax);
                mrun = cmax; lrun *= r;
#pragma unroll
                for (int d = 0; d < D; ++d) acc[d] *= r;
            }
#pragma unroll
            for (int j = 0; j < FSUB; ++j) {
                float p = __expf(sx[j] - mrun);
                lrun += p;
#pragma unroll
                for (int d = 0; d < D; d += 4) {
                    float4 vv = *reinterpret_cast<const float4*>(&Vt[j0 + j][d]);
                    acc[d] = fmaf(p, vv.x, acc[d]);
                    acc[d+1] = fmaf(p, vv.y, acc[d+1]);
                    acc[d+2] = fmaf(p, vv.z, acc[d+2]);
                    acc[d+3] = fmaf(p, vv.w, acc[d+3]);
                }
            }
        }
    }
    const float invl = 1.0f / lrun;
    float* op = O + ((size_t)bh * S + qrow) * D;
#pragma unroll
    for (int d = 0; d < D; d += 4) {
        float4 t;
        t.x = acc[d] * invl; t.y = acc[d+1] * invl; t.z = acc[d+2] * invl; t.w = acc[d+3] * invl;
        *reinterpret_cast<float4*>(op + d) = t;
    }
}

extern "C" void kernel_launch(void* const* d_in, const int* in_sizes, int n_in,
                              void* d_out, int out_size, void* d_ws, size_t ws_size,
                              hipStream_t stream) {
    const float* q = (const float*)d_in[0];
    const float* k = (const float*)d_in[1];
    const float* v = (const float*)d_in[2];
    const float* m = (const float*)d_in[3];
    float* out = (float*)d_out;
    if (ws_size >= WS_NEED) {
        short* kimg = (short*)d_ws;
        short* vimg = kimg + IMG_SH;
        conv_kv<<<dim3(2 * NBH * NKT), dim3(256), 0, stream>>>(k, v, kimg, vimg);
        attn_img<<<dim3(NBH * NQT), dim3(256), 0, stream>>>(q, m, kimg, vimg, out);
    } else {
        attn_f32<<<dim3(NBH * (S / FQT)), dim3(256), 0, stream>>>(q, k, v, m, out);
    }
}